// Round 1
// baseline (905.542 us; speedup 1.0000x reference)
//
#include <hip/hip_runtime.h>
#include <float.h>

// Viterbi decode: B=1024 sequences, T=1024 steps, K=48 tags.
// Forward: one wave per batch element, lane = next-tag (48/64 lanes active).
//   fv vector exchanged via per-wave LDS (broadcast reads), trans row in VGPRs.
//   Backpointers (uint8) -> d_ws. Terminal argmax via 64-lane butterfly.
// Backward: one wave per batch element; loads full bptr row per step
//   (chain-independent, prefetched in chunks of 16), dependent op is a shuffle.

#define BB 1024
#define TT 1024
#define KK 48
#define NEGV -10000.0f

__global__ __launch_bounds__(256) void viterbi_fwd(
    const float* __restrict__ feats, const float* __restrict__ trans,
    float* __restrict__ scores, unsigned char* __restrict__ bptr,
    int* __restrict__ bestArr) {
  __shared__ float fvbuf[4][64];
  const int lane = threadIdx.x & 63;
  const int w = threadIdx.x >> 6;
  const int b = blockIdx.x * 4 + w;
  const int rl = (lane < KK) ? lane : (KK - 1);  // clamped lane for loads

  // Load this lane's transition row trans[next=rl][0..47] into registers.
  float tr[KK];
#pragma unroll
  for (int j = 0; j < 12; ++j) {
    float4 t4 = *(const float4*)(trans + rl * KK + 4 * j);
    tr[4 * j + 0] = t4.x; tr[4 * j + 1] = t4.y;
    tr[4 * j + 2] = t4.z; tr[4 * j + 3] = t4.w;
  }
  const float tstop = trans[(KK - 1) * KK + rl];  // transitions[STOP][rl]

  // init forward_var
  if (lane < KK) fvbuf[w][lane] = (lane == 46) ? 0.0f : NEGV;
  __builtin_amdgcn_wave_barrier();

  const float* fp = feats + (size_t)b * TT * KK + rl;
  unsigned char* bp = bptr + (size_t)b * TT * KK + lane;

  float fv = NEGV;  // this lane's forward var (valid for lane<48)

  for (int t = 0; t < TT; ++t) {
    // Read full fv vector (uniform-address broadcast LDS reads).
    float fvr[KK];
#pragma unroll
    for (int j = 0; j < 12; ++j) {
      float4 v4 = *(const float4*)(&fvbuf[w][4 * j]);
      fvr[4 * j + 0] = v4.x; fvr[4 * j + 1] = v4.y;
      fvr[4 * j + 2] = v4.z; fvr[4 * j + 3] = v4.w;
    }
    __builtin_amdgcn_wave_barrier();

    // argmax over prev (ascending, strict > => first-index like np.argmax)
    float best_s = fvr[0] + tr[0];
    int bpi = 0;
#pragma unroll
    for (int p = 1; p < KK; ++p) {
      float s = fvr[p] + tr[p];
      if (s > best_s) { best_s = s; bpi = p; }
    }

    float feat = fp[(size_t)t * KK];
    float nfv = best_s + feat;
    if (lane < KK) {
      bp[(size_t)t * KK] = (unsigned char)bpi;
      fvbuf[w][lane] = nfv;
      fv = nfv;
    }
    __builtin_amdgcn_wave_barrier();
  }

  // Epilogue: terminal = F_T + transitions[STOP]; first-index argmax.
  float v = (lane < KK) ? (fv + tstop) : -FLT_MAX;
  int idx = lane;
#pragma unroll
  for (int off = 32; off >= 1; off >>= 1) {
    float ov = __shfl_xor(v, off);
    int oi = __shfl_xor(idx, off);
    bool take = (ov > v) || (ov == v && oi < idx);
    v = take ? ov : v;
    idx = take ? oi : idx;
  }
  if (lane == 0) {
    scores[b] = v;
    bestArr[b] = idx;
  }
}

__global__ __launch_bounds__(256) void viterbi_bwd(
    const unsigned char* __restrict__ bptr, const int* __restrict__ bestArr,
    float* __restrict__ path) {
  const int lane = threadIdx.x & 63;
  const int w = threadIdx.x >> 6;
  const int b = blockIdx.x * 4 + w;
  const int rl = (lane < KK) ? lane : (KK - 1);

  const unsigned char* bp = bptr + (size_t)b * TT * KK + rl;
  float* po = path + (size_t)b * TT;
  int tag = bestArr[b];  // wave-uniform

  const int CH = 16;
  int cur[CH], nxt[CH];
#pragma unroll
  for (int j = 0; j < CH; ++j) cur[j] = bp[(size_t)(TT - CH + j) * KK];

  for (int tb = TT - CH; tb >= 0; tb -= CH) {
    if (tb >= CH) {
#pragma unroll
      for (int j = 0; j < CH; ++j) nxt[j] = bp[(size_t)(tb - CH + j) * KK];
    }
    float myv = 0.0f;
#pragma unroll
    for (int j = CH - 1; j >= 0; --j) {
      if (lane == j) myv = (float)tag;  // path[tb+j] = tag before update
      tag = __shfl(cur[j], tag);        // tag = bptrs[tb+j][tag]
    }
    if (lane < CH) po[tb + lane] = myv;
    if (tb >= CH) {
#pragma unroll
      for (int j = 0; j < CH; ++j) cur[j] = nxt[j];
    }
  }
}

extern "C" void kernel_launch(void* const* d_in, const int* in_sizes, int n_in,
                              void* d_out, int out_size, void* d_ws,
                              size_t ws_size, hipStream_t stream) {
  const float* feats = (const float*)d_in[0];
  const float* trans = (const float*)d_in[1];
  float* out = (float*)d_out;  // [0,1024): scores; [1024, 1024+1024*1024): paths

  unsigned char* bptr = (unsigned char*)d_ws;                       // 50.3 MB
  int* bestArr = (int*)((char*)d_ws + (size_t)BB * TT * KK);        // 4 KB

  viterbi_fwd<<<dim3(BB / 4), dim3(256), 0, stream>>>(feats, trans, out, bptr,
                                                      bestArr);
  viterbi_bwd<<<dim3(BB / 4), dim3(256), 0, stream>>>(bptr, bestArr,
                                                      out + BB);
}

// Round 2
// 888.371 us; speedup vs baseline: 1.0193x; 1.0193x over previous
//
#include <hip/hip_runtime.h>
#include <float.h>

// Viterbi decode: B=1024, T=1024, K=48.
// Forward: one wave per b (block=64, launch_bounds(64,1) so trans row stays in
//   VGPRs), fv broadcast via per-wave LDS, 4 independent argmax chains of 12
//   (exact first-index ties), feat prefetched 4 steps ahead.
// Backward: chunked scan. Pass1: per-(b,chunk) composed tag map (48 entries).
//   Pass2: per-b sequential compose over 16 chunk maps. Pass3: per-(b,chunk)
//   re-walk with known entry tag, coalesced emit.

#define BB 1024
#define TT 1024
#define KK 48
#define CC 16   // chunks per sequence
#define LL 64   // steps per chunk (CC*LL == TT), == wave size
#define NEGV -10000.0f

__global__ __launch_bounds__(64, 1) void viterbi_fwd(
    const float* __restrict__ feats, const float* __restrict__ trans,
    float* __restrict__ scores, unsigned char* __restrict__ bptr,
    int* __restrict__ bestArr) {
  __shared__ __align__(16) float fvbuf[64];
  const int lane = threadIdx.x;
  const int b = blockIdx.x;
  const int rl = (lane < KK) ? lane : (KK - 1);

  // Transition row trans[next=rl][0..47] resident in VGPRs.
  float tr[KK];
#pragma unroll
  for (int j = 0; j < 12; ++j) {
    float4 t4 = *(const float4*)(trans + rl * KK + 4 * j);
    tr[4 * j + 0] = t4.x; tr[4 * j + 1] = t4.y;
    tr[4 * j + 2] = t4.z; tr[4 * j + 3] = t4.w;
  }
  const float tstop = trans[(KK - 1) * KK + rl];

  if (lane < KK) fvbuf[lane] = (lane == 46) ? 0.0f : NEGV;
  __builtin_amdgcn_wave_barrier();

  const float* fp = feats + (size_t)b * TT * KK + rl;
  unsigned char* bp = bptr + (size_t)b * TT * KK + lane;

  // feat prefetch ring, distance 4 (static indices via 4x unroll)
  float fbuf[4];
#pragma unroll
  for (int k = 0; k < 4; ++k) fbuf[k] = fp[(size_t)k * KK];

  float fv = NEGV;
  for (int t0 = 0; t0 < TT; t0 += 4) {
#pragma unroll
    for (int u = 0; u < 4; ++u) {
      const int t = t0 + u;
      // broadcast-read full fv vector from LDS
      float fvr[KK];
#pragma unroll
      for (int j = 0; j < 12; ++j) {
        float4 v4 = *(const float4*)(&fvbuf[4 * j]);
        fvr[4 * j + 0] = v4.x; fvr[4 * j + 1] = v4.y;
        fvr[4 * j + 2] = v4.z; fvr[4 * j + 3] = v4.w;
      }
      __builtin_amdgcn_wave_barrier();

      // 4 independent argmax chains of 12 (first-index ties exact:
      // within a chain strict > keeps first; across chains indices ascend,
      // so take the later chain only on strict >).
      float bs0 = fvr[0] + tr[0], bs1 = fvr[12] + tr[12];
      float bs2 = fvr[24] + tr[24], bs3 = fvr[36] + tr[36];
      int bi0 = 0, bi1 = 12, bi2 = 24, bi3 = 36;
#pragma unroll
      for (int p = 1; p < 12; ++p) {
        float s0 = fvr[p] + tr[p];
        float s1 = fvr[12 + p] + tr[12 + p];
        float s2 = fvr[24 + p] + tr[24 + p];
        float s3 = fvr[36 + p] + tr[36 + p];
        if (s0 > bs0) { bs0 = s0; bi0 = p; }
        if (s1 > bs1) { bs1 = s1; bi1 = 12 + p; }
        if (s2 > bs2) { bs2 = s2; bi2 = 24 + p; }
        if (s3 > bs3) { bs3 = s3; bi3 = 36 + p; }
      }
      bool c1 = bs1 > bs0;
      float m01 = c1 ? bs1 : bs0; int i01 = c1 ? bi1 : bi0;
      bool c3 = bs3 > bs2;
      float m23 = c3 ? bs3 : bs2; int i23 = c3 ? bi3 : bi2;
      bool cf = m23 > m01;
      float m = cf ? m23 : m01; int bpi = cf ? i23 : i01;

      float nfv = m + fbuf[u];
      // prefetch feat for t+4 (offset clamped to avoid OOB on last steps)
      size_t toff = (t + 4 < TT) ? (size_t)(t + 4) * KK : 0;
      fbuf[u] = fp[toff];

      if (lane < KK) {
        bp[(size_t)t * KK] = (unsigned char)bpi;
        fvbuf[lane] = nfv;
        fv = nfv;
      }
      __builtin_amdgcn_wave_barrier();
    }
  }

  // terminal = F_T + transitions[STOP]; first-index argmax via butterfly
  float v = (lane < KK) ? (fv + tstop) : -FLT_MAX;
  int idx = lane;
#pragma unroll
  for (int off = 32; off >= 1; off >>= 1) {
    float ov = __shfl_xor(v, off);
    int oi = __shfl_xor(idx, off);
    bool take = (ov > v) || (ov == v && oi < idx);
    v = take ? ov : v;
    idx = take ? oi : idx;
  }
  if (lane == 0) {
    scores[b] = v;
    bestArr[b] = idx;
  }
}

// Pass 1: composed tag map per (b, chunk): map[x] = tag after applying rows
// (c*LL+LL-1 .. c*LL) starting from entry tag x.
__global__ __launch_bounds__(256) void bwd_map(
    const unsigned char* __restrict__ bptr, unsigned char* __restrict__ cmap) {
  const int lane = threadIdx.x & 63;
  const int wg = blockIdx.x * 4 + (threadIdx.x >> 6);  // 0..B*CC-1
  const int b = wg >> 4;
  const int c = wg & (CC - 1);
  const int rl = (lane < KK) ? lane : (KK - 1);
  const unsigned char* bp =
      bptr + ((size_t)b * TT + (size_t)c * LL) * KK + rl;

  int x = rl;
  const int CH = 16;
  int cur[CH], nxt[CH];
#pragma unroll
  for (int j = 0; j < CH; ++j) cur[j] = bp[(size_t)(LL - CH + j) * KK];
  for (int tb = LL - CH; tb >= 0; tb -= CH) {
    if (tb >= CH) {
#pragma unroll
      for (int j = 0; j < CH; ++j) nxt[j] = bp[(size_t)(tb - CH + j) * KK];
    }
#pragma unroll
    for (int j = CH - 1; j >= 0; --j) x = __shfl(cur[j], x);
    if (tb >= CH) {
#pragma unroll
      for (int j = 0; j < CH; ++j) cur[j] = nxt[j];
    }
  }
  if (lane < KK) cmap[(size_t)wg * KK + lane] = (unsigned char)x;
}

// Pass 2: per-b sequential compose over chunk maps; entry[b][c] = carry tag
// entering chunk c.
__global__ __launch_bounds__(256) void bwd_entry(
    const unsigned char* __restrict__ cmap, const int* __restrict__ bestArr,
    int* __restrict__ entry) {
  const int lane = threadIdx.x & 63;
  const int b = blockIdx.x * 4 + (threadIdx.x >> 6);
  const int rl = (lane < KK) ? lane : (KK - 1);

  int rows[CC];
#pragma unroll
  for (int c = 0; c < CC; ++c)
    rows[c] = cmap[((size_t)b * CC + c) * KK + rl];

  int tag = bestArr[b];
  int ev = 0;
#pragma unroll
  for (int c = CC - 1; c >= 0; --c) {
    if (lane == c) ev = tag;
    tag = __shfl(rows[c], tag);
  }
  if (lane < CC) entry[b * CC + lane] = ev;
}

// Pass 3: re-walk chunk with known entry tag, emit path (lane j holds step
// c*LL+j; LL == 64 == wave size -> fully coalesced store).
__global__ __launch_bounds__(256) void bwd_emit(
    const unsigned char* __restrict__ bptr, const int* __restrict__ entry,
    float* __restrict__ path) {
  const int lane = threadIdx.x & 63;
  const int wg = blockIdx.x * 4 + (threadIdx.x >> 6);
  const int b = wg >> 4;
  const int c = wg & (CC - 1);
  const int rl = (lane < KK) ? lane : (KK - 1);
  const unsigned char* bp =
      bptr + ((size_t)b * TT + (size_t)c * LL) * KK + rl;

  int x = entry[b * CC + c];
  int myv = 0;
  const int CH = 16;
  int cur[CH], nxt[CH];
#pragma unroll
  for (int j = 0; j < CH; ++j) cur[j] = bp[(size_t)(LL - CH + j) * KK];
  for (int tb = LL - CH; tb >= 0; tb -= CH) {
    if (tb >= CH) {
#pragma unroll
      for (int j = 0; j < CH; ++j) nxt[j] = bp[(size_t)(tb - CH + j) * KK];
    }
#pragma unroll
    for (int j = CH - 1; j >= 0; --j) {
      if (lane == tb + j) myv = x;
      x = __shfl(cur[j], x);
    }
    if (tb >= CH) {
#pragma unroll
      for (int j = 0; j < CH; ++j) cur[j] = nxt[j];
    }
  }
  path[(size_t)b * TT + (size_t)c * LL + lane] = (float)myv;
}

extern "C" void kernel_launch(void* const* d_in, const int* in_sizes, int n_in,
                              void* d_out, int out_size, void* d_ws,
                              size_t ws_size, hipStream_t stream) {
  const float* feats = (const float*)d_in[0];
  const float* trans = (const float*)d_in[1];
  float* out = (float*)d_out;  // [0,1024): scores; then paths [B*T]

  unsigned char* bptr = (unsigned char*)d_ws;                 // 50,331,648 B
  char* p = (char*)d_ws + (size_t)BB * TT * KK;
  int* bestArr = (int*)p;                                     // 4 KB
  p += BB * sizeof(int);
  unsigned char* cmap = (unsigned char*)p;                    // 786,432 B
  p += (size_t)BB * CC * KK;
  int* entry = (int*)p;                                       // 64 KB

  viterbi_fwd<<<dim3(BB), dim3(64), 0, stream>>>(feats, trans, out, bptr,
                                                 bestArr);
  bwd_map<<<dim3(BB * CC / 4), dim3(256), 0, stream>>>(bptr, cmap);
  bwd_entry<<<dim3(BB / 4), dim3(256), 0, stream>>>(cmap, bestArr, entry);
  bwd_emit<<<dim3(BB * CC / 4), dim3(256), 0, stream>>>(bptr, entry,
                                                        out + BB);
}